// Round 8
// baseline (140.662 us; speedup 1.0000x reference)
//
#include <hip/hip_runtime.h>

typedef float f32x2 __attribute__((ext_vector_type(2)));

#define K_CW 256
#define NJ (K_CW / 2)   // 128 codeword PAIRS (packed along k)
#define PPT 2           // points per thread: B/2 threads = 32 waves/CU, one round

// Packed-pair codebook entry, 48 B: {c0[2j],c0[2j+1]} ... {cs[2j],cs[2j+1]}.
// All pairs sit at even-dword offsets -> s_load puts them in even-aligned
// SGPR pairs, directly usable as VOP3P 64-bit scalar sources.
struct PK2 { f32x2 c0, c1, c2, c3, cs, pad; };

// VOP3P packed fp32 helpers. Each is TWO independent IEEE-rounded fp32 ops
// (identical rounding to the scalar v_mul/v_fma/v_add) in ONE instruction.
// The "s" constraint binds the codebook pair as an SGPR-pair source (VOP3P
// allows 1 SGPR source) -> zero broadcast movs. Non-volatile, pure -> the
// scheduler places them freely by data deps.
__device__ __forceinline__ f32x2 pk_mul_vs(f32x2 a, f32x2 b) {
    f32x2 d; asm("v_pk_mul_f32 %0, %1, %2" : "=v"(d) : "v"(a), "s"(b)); return d;
}
__device__ __forceinline__ f32x2 pk_fma_vsv(f32x2 a, f32x2 b, f32x2 c) {
    f32x2 d; asm("v_pk_fma_f32 %0, %1, %2, %3" : "=v"(d) : "v"(a), "s"(b), "v"(c)); return d;
}
__device__ __forceinline__ f32x2 pk_fma_vvv(f32x2 a, f32x2 b, f32x2 c) {
    f32x2 d; asm("v_pk_fma_f32 %0, %1, %2, %3" : "=v"(d) : "v"(a), "v"(b), "v"(c)); return d;
}
__device__ __forceinline__ f32x2 pk_add_vs(f32x2 a, f32x2 b) {
    f32x2 d; asm("v_pk_add_f32 %0, %1, %2" : "=v"(d) : "v"(a), "s"(b)); return d;
}

// Build packed-pair codebook in ws. csq uses numpy rounding:
// ((c0*c0 + c1*c1) + c2*c2) + c3*c3 (sequential adds of rounded squares).
__global__ void vq_pack_kernel(const float* __restrict__ tlut, float* __restrict__ pk) {
    int k = threadIdx.x;  // 256 threads, 1 block
    float c0 = tlut[k * 4 + 0];
    float c1 = tlut[k * 4 + 1];
    float c2 = tlut[k * 4 + 2];
    float c3 = tlut[k * 4 + 3];
    float s = __fadd_rn(__fadd_rn(__fadd_rn(__fmul_rn(c0, c0), __fmul_rn(c1, c1)),
                                  __fmul_rn(c2, c2)),
                        __fmul_rn(c3, c3));
    const int j = k >> 1, o = k & 1;
    float* e = pk + j * 12;     // 12 dwords per pair entry
    e[0 + o] = c0; e[2 + o] = c1; e[4 + o] = c2; e[6 + o] = c3; e[8 + o] = s;
    if (o == 0) { e[10] = 0.f; e[11] = 0.f; }
}

__global__ __launch_bounds__(256, 8) void vq_argmin_kernel(
    const float* __restrict__ X,
    const float* __restrict__ tlut,
    const float* __restrict__ pk,
    float* __restrict__ outX,   // [B,4] reconstruction
    float* __restrict__ outS,   // [B] state, stored as float
    int B) {
    // Lean structure: no split-K, no LDS, no barriers. 2048 blocks x 256 thr
    // = 524288 threads = 8192 waves = 32 waves/CU, all resident, one round.
    // Packed-k inner loop: ~26 instr per codeword-pair per 2 points vs ~38
    // scalar -> attacks the measured per-CU instruction-delivery bound.
    const int g = blockIdx.x * 256 + threadIdx.x;   // point-group id
    const int stride = B / PPT;                     // strided points -> coalesced

    const float4* __restrict__ X4 = reinterpret_cast<const float4*>(X);
    const float4* __restrict__ T4 = reinterpret_cast<const float4*>(tlut);
    const PK2* __restrict__ PKB = reinterpret_cast<const PK2*>(pk);

    // Loop-invariant broadcast pairs: {x,x} so one pk op works on {k_even,k_odd}.
    f32x2 xb0[PPT], xb1[PPT], xb2[PPT], xb3[PPT], xsqb[PPT];
    float bestd[PPT];
    int besti[PPT];

    #pragma unroll
    for (int i = 0; i < PPT; ++i) {
        const float4 xv = X4[g + i * stride];
        // x_sq with numpy rounding: sequential adds of rounded squares
        const float xsq =
            __fadd_rn(__fadd_rn(__fadd_rn(__fmul_rn(xv.x, xv.x), __fmul_rn(xv.y, xv.y)),
                                __fmul_rn(xv.z, xv.z)),
                      __fmul_rn(xv.w, xv.w));
        xb0[i] = f32x2{xv.x, xv.x};
        xb1[i] = f32x2{xv.y, xv.y};
        xb2[i] = f32x2{xv.z, xv.z};
        xb3[i] = f32x2{xv.w, xv.w};
        xsqb[i] = f32x2{xsq, xsq};
        bestd[i] = __builtin_inff();
        besti[i] = 0;
    }
    const f32x2 m2 = f32x2{-2.0f, -2.0f};  // materialized once

    #pragma unroll 16
    for (int j = 0; j < NJ; ++j) {
        const PK2 e = PKB[j];      // uniform -> s_load_dwordx8 + dwordx4
        const int k0 = j * 2;
        #pragma unroll
        for (int i = 0; i < PPT; ++i) {
            // cross for BOTH codewords of the pair, numpy rounding per half:
            // mul_rn then ascending fma chain (identical to the scalar recipe)
            f32x2 cr = pk_mul_vs(xb0[i], e.c0);
            cr = pk_fma_vsv(xb1[i], e.c1, cr);
            cr = pk_fma_vsv(xb2[i], e.c2, cr);
            cr = pk_fma_vsv(xb3[i], e.c3, cr);
            // t2 = fma(-2, cross, xsq); d = t2 + csq  (both halves, rn)
            const f32x2 t2 = pk_fma_vvv(m2, cr, xsqb[i]);
            const f32x2 d = pk_add_vs(t2, e.cs);
            // argmin, first occurrence: even k before odd k, strict '<'
            besti[i] = (d[0] < bestd[i]) ? k0 : besti[i];
            bestd[i] = fminf(d[0], bestd[i]);
            besti[i] = (d[1] < bestd[i]) ? (k0 + 1) : besti[i];
            bestd[i] = fminf(d[1], bestd[i]);
        }
    }

    #pragma unroll
    for (int i = 0; i < PPT; ++i) {
        const int p = g + i * stride;
        reinterpret_cast<float4*>(outX)[p] = T4[besti[i]];  // tlut is L1-resident
        outS[p] = (float)besti[i];
    }
}

extern "C" void kernel_launch(void* const* d_in, const int* in_sizes, int n_in,
                              void* d_out, int out_size, void* d_ws, size_t ws_size,
                              hipStream_t stream) {
    const float* X    = (const float*)d_in[0];   // [B,4]
    const float* tlut = (const float*)d_in[1];   // [256,4]
    const int B = in_sizes[0] / 4;

    float* outX = (float*)d_out;          // first B*4 floats: hatX
    float* outS = outX + (size_t)B * 4;   // next B floats: state (as float)

    float* pk = (float*)d_ws;             // 128 * 12 floats packed-pair codebook

    vq_pack_kernel<<<1, 256, 0, stream>>>(tlut, pk);

    const int groups = B / PPT;           // 524288 point-groups
    const int grid = groups / 256;        // 2048 blocks of 256 threads
    vq_argmin_kernel<<<grid, 256, 0, stream>>>(X, tlut, pk, outX, outS, B);
}

// Round 9
// 129.318 us; speedup vs baseline: 1.0877x; 1.0877x over previous
//
#include <hip/hip_runtime.h>

typedef float f32x2 __attribute__((ext_vector_type(2)));

#define K_CW 256
#define NJ (K_CW / 2)   // 128 codeword PAIRS (packed along k)
#define PPT 2           // points per thread: B/2 threads = 32 waves/CU, one round

// VOP3P packed fp32: each is TWO independent IEEE-RN fp32 ops in ONE
// instruction (bit-exact per half vs scalar v_mul/v_fma/v_add -- validated on
// gfx950 by round 8: passed, absmax=0.0). ALL-VGPR constraints: zero SGPR
// pressure, no spill pathway (round 8's "s"-constraint variant spilled 68 MB
// to scratch). Pure asm (no volatile) -> scheduler places by data deps.
__device__ __forceinline__ f32x2 pk_mul(f32x2 a, f32x2 b) {
    f32x2 d; asm("v_pk_mul_f32 %0, %1, %2" : "=v"(d) : "v"(a), "v"(b)); return d;
}
__device__ __forceinline__ f32x2 pk_fma(f32x2 a, f32x2 b, f32x2 c) {
    f32x2 d; asm("v_pk_fma_f32 %0, %1, %2, %3" : "=v"(d) : "v"(a), "v"(b), "v"(c)); return d;
}
__device__ __forceinline__ f32x2 pk_add(f32x2 a, f32x2 b) {
    f32x2 d; asm("v_pk_add_f32 %0, %1, %2" : "=v"(d) : "v"(a), "v"(b)); return d;
}

// Single fused kernel. Packed-pair codebook staged in LDS, entry stride 48 B
// (16B-aligned): [c0p][c1p][c2p][c3p][csp][pad] as f32x2 -> reads merge to
// ds_read_b128 + ds_read_b128 + ds_read_b64, uniform address = broadcast,
// compiler-managed partial lgkmcnt waits. Inner loop: 6 instructions per
// codeword per point (vs 9 scalar) -> attacks the measured per-CU
// instruction-delivery cap (VALUBusy pinned ~75% across 4 wait mechanisms).
__global__ __launch_bounds__(256, 8) void vq_argmin_kernel(
    const float* __restrict__ X,
    const float* __restrict__ tlut,
    float* __restrict__ outX,   // [B,4] reconstruction
    float* __restrict__ outS,   // [B] state, stored as float
    int B) {
    __shared__ f32x2 scb[NJ * 6];   // 6 KB packed-pair codebook

    const int t = threadIdx.x;
    const int g = blockIdx.x * 256 + t;   // point-group id
    const int stride = B / PPT;           // strided points -> coalesced

    const float4* __restrict__ X4 = reinterpret_cast<const float4*>(X);
    const float4* __restrict__ T4 = reinterpret_cast<const float4*>(tlut);

    // Stage: thread k (<256) owns codeword k, writes its half of pair j=k>>1.
    // csq uses numpy rounding: ((c0*c0 + c1*c1) + c2*c2) + c3*c3 (sequential
    // rounded adds).
    {
        const float4 cv = T4[t];
        const float s = __fadd_rn(__fadd_rn(__fadd_rn(__fmul_rn(cv.x, cv.x),
                                                      __fmul_rn(cv.y, cv.y)),
                                            __fmul_rn(cv.z, cv.z)),
                                  __fmul_rn(cv.w, cv.w));
        const int j = t >> 1, o = t & 1;
        float* e = reinterpret_cast<float*>(&scb[j * 6]);
        e[0 + o] = cv.x; e[2 + o] = cv.y; e[4 + o] = cv.z; e[6 + o] = cv.w;
        e[8 + o] = s;
        if (o == 0) { e[10] = 0.f; e[11] = 0.f; }
    }

    // Loop-invariant broadcast pairs {x,x}: one pk op covers {k_even,k_odd}.
    f32x2 xb0[PPT], xb1[PPT], xb2[PPT], xb3[PPT], xsqb[PPT];
    float bestd[PPT];
    int besti[PPT];

    #pragma unroll
    for (int i = 0; i < PPT; ++i) {
        const float4 xv = X4[g + i * stride];
        // x_sq with numpy rounding: sequential adds of rounded squares
        const float xsq =
            __fadd_rn(__fadd_rn(__fadd_rn(__fmul_rn(xv.x, xv.x), __fmul_rn(xv.y, xv.y)),
                                __fmul_rn(xv.z, xv.z)),
                      __fmul_rn(xv.w, xv.w));
        xb0[i] = f32x2{xv.x, xv.x};
        xb1[i] = f32x2{xv.y, xv.y};
        xb2[i] = f32x2{xv.z, xv.z};
        xb3[i] = f32x2{xv.w, xv.w};
        xsqb[i] = f32x2{xsq, xsq};
        bestd[i] = __builtin_inff();
        besti[i] = 0;
    }
    const f32x2 m2 = f32x2{-2.0f, -2.0f};

    __syncthreads();

    #pragma unroll 8
    for (int j = 0; j < NJ; ++j) {
        // Adjacent f32x2 at 16B-aligned entry base -> b128/b128/b64 broadcasts.
        const f32x2 c0p = scb[j * 6 + 0];
        const f32x2 c1p = scb[j * 6 + 1];
        const f32x2 c2p = scb[j * 6 + 2];
        const f32x2 c3p = scb[j * 6 + 3];
        const f32x2 csp = scb[j * 6 + 4];
        const int k0 = j * 2;
        #pragma unroll
        for (int i = 0; i < PPT; ++i) {
            // cross for both codewords, numpy rounding per half:
            // mul_rn then ascending fma chain (identical to scalar recipe)
            f32x2 cr = pk_mul(xb0[i], c0p);
            cr = pk_fma(xb1[i], c1p, cr);
            cr = pk_fma(xb2[i], c2p, cr);
            cr = pk_fma(xb3[i], c3p, cr);
            // t2 = fma(-2, cross, xsq); d = t2 + csq (both halves, rn)
            const f32x2 t2 = pk_fma(m2, cr, xsqb[i]);
            const f32x2 d = pk_add(t2, csp);
            // argmin, first occurrence: even k before odd k, strict '<'
            // (constant-index vector extracts -> registers, no scratch)
            besti[i] = (d[0] < bestd[i]) ? k0 : besti[i];
            bestd[i] = fminf(d[0], bestd[i]);
            besti[i] = (d[1] < bestd[i]) ? (k0 + 1) : besti[i];
            bestd[i] = fminf(d[1], bestd[i]);
        }
    }

    #pragma unroll
    for (int i = 0; i < PPT; ++i) {
        const int p = g + i * stride;
        reinterpret_cast<float4*>(outX)[p] = T4[besti[i]];  // tlut is L1-resident
        outS[p] = (float)besti[i];
    }
}

extern "C" void kernel_launch(void* const* d_in, const int* in_sizes, int n_in,
                              void* d_out, int out_size, void* d_ws, size_t ws_size,
                              hipStream_t stream) {
    const float* X    = (const float*)d_in[0];   // [B,4]
    const float* tlut = (const float*)d_in[1];   // [256,4]
    const int B = in_sizes[0] / 4;

    float* outX = (float*)d_out;          // first B*4 floats: hatX
    float* outS = outX + (size_t)B * 4;   // next B floats: state (as float)

    const int groups = B / PPT;           // 524288 point-groups
    const int grid = groups / 256;        // 2048 blocks of 256 threads
    vq_argmin_kernel<<<grid, 256, 0, stream>>>(X, tlut, outX, outS, B);
}